// Round 1
// baseline (415.897 us; speedup 1.0000x reference)
//
#include <hip/hip_runtime.h>
#include <hip/hip_bf16.h>
#include <stdint.h>

typedef __bf16 bf16_t;
typedef __bf16 bf16x8 __attribute__((ext_vector_type(8)));
typedef float  f32x4  __attribute__((ext_vector_type(4)));

#define K_DIM 4096
#define N_DIM 4096

// ---------------------------------------------------------------------------
// Kernel 1: x fp32 -> bf16 (vectorized: 8 elems/thread, float4 loads, 16B store)
// ---------------------------------------------------------------------------
__global__ __launch_bounds__(256) void convert_x_kernel(const float* __restrict__ x,
                                                        bf16_t* __restrict__ xb) {
    const long long i = ((long long)blockIdx.x * blockDim.x + threadIdx.x) * 8;
    float4 a = *(const float4*)(x + i);
    float4 b = *(const float4*)(x + i + 4);
    bf16x8 o;
    o[0] = (bf16_t)a.x; o[1] = (bf16_t)a.y; o[2] = (bf16_t)a.z; o[3] = (bf16_t)a.w;
    o[4] = (bf16_t)b.x; o[5] = (bf16_t)b.y; o[6] = (bf16_t)b.z; o[7] = (bf16_t)b.w;
    *(bf16x8*)(xb + i) = o;
}

// ---------------------------------------------------------------------------
// Kernel 2: weight row -> sign (bf16, exact) + per-row mean|w| (fp32)
// One block (256 thr) per output row; 16 elems/thread.
// ---------------------------------------------------------------------------
__device__ __forceinline__ bf16_t sgn_bf16(float f) {
    return (bf16_t)((f > 0.f) ? 1.f : ((f < 0.f) ? -1.f : 0.f));
}

__global__ __launch_bounds__(256) void convert_w_kernel(const float* __restrict__ w,
                                                        bf16_t* __restrict__ wb,
                                                        float* __restrict__ s) {
    const int row = blockIdx.x;
    const int tid = threadIdx.x;
    const float* wr = w + (long long)row * K_DIM;
    bf16_t* wbr = wb + (long long)row * K_DIM;
    const int off = tid * 16;

    float sum = 0.f;
    bf16x8 o0, o1;
    #pragma unroll
    for (int j = 0; j < 2; ++j) {
        float4 v = *(const float4*)(wr + off + j * 4);
        sum += fabsf(v.x) + fabsf(v.y) + fabsf(v.z) + fabsf(v.w);
        o0[j * 4 + 0] = sgn_bf16(v.x); o0[j * 4 + 1] = sgn_bf16(v.y);
        o0[j * 4 + 2] = sgn_bf16(v.z); o0[j * 4 + 3] = sgn_bf16(v.w);
    }
    #pragma unroll
    for (int j = 0; j < 2; ++j) {
        float4 v = *(const float4*)(wr + off + 8 + j * 4);
        sum += fabsf(v.x) + fabsf(v.y) + fabsf(v.z) + fabsf(v.w);
        o1[j * 4 + 0] = sgn_bf16(v.x); o1[j * 4 + 1] = sgn_bf16(v.y);
        o1[j * 4 + 2] = sgn_bf16(v.z); o1[j * 4 + 3] = sgn_bf16(v.w);
    }
    *(bf16x8*)(wbr + off)     = o0;
    *(bf16x8*)(wbr + off + 8) = o1;

    // wave reduce (64 lanes) then cross-wave via LDS
    #pragma unroll
    for (int d = 32; d > 0; d >>= 1) sum += __shfl_down(sum, d);
    __shared__ float red[4];
    const int lane = tid & 63, wid = tid >> 6;
    if (lane == 0) red[wid] = sum;
    __syncthreads();
    if (tid == 0) s[row] = (red[0] + red[1] + red[2] + red[3]) * (1.0f / (float)K_DIM);
}

// ---------------------------------------------------------------------------
// Kernel 3: C[m][n] = s[n] * sum_k Xb[m][k] * Wb[n][k]   (B^T-layout bf16 GEMM)
// m97 structure: 128x128 tile, BK=64, 4 waves (2x2), 4x4 frags of 16x16x32,
// global_load_lds width=16 staging (linear LDS dest), 2-barrier K-loop.
// ---------------------------------------------------------------------------
__global__ __launch_bounds__(256) void bitlinear_gemm_kernel(
    const bf16_t* __restrict__ A,      // [M][K] bf16
    const bf16_t* __restrict__ B,      // [N][K] bf16 (signs)
    const float*  __restrict__ scale,  // [N] fp32
    float* __restrict__ C,             // [M][N] fp32
    int M)
{
    constexpr int BK = 64;
    __shared__ bf16_t As[128 * BK];   // 16 KiB
    __shared__ bf16_t Bs[128 * BK];   // 16 KiB

    const int tid  = threadIdx.x;
    const int lane = tid & 63;
    const int wid  = tid >> 6;
    const int wr   = wid >> 1;   // wave row 0..1 (64-row strip)
    const int wc   = wid & 1;    // wave col 0..1 (64-col strip)

    const int ntn = N_DIM / 128;            // 32
    const int tm  = blockIdx.x / ntn;
    const int tn  = blockIdx.x % ntn;
    const long long m0 = (long long)tm * 128;
    const long long n0 = (long long)tn * 128;

    // staging geometry: per wave, inst i covers LDS bytes [wid*4096 + i*1024, +1024)
    // = tile rows [wid*32 + i*8, +8), lane l -> row +(l>>3), col elems (l&7)*8
    const int srow = wid * 32 + (lane >> 3);
    const int scol = (lane & 7) * 8;
    const bf16_t* gA = A + (m0 + srow) * K_DIM + scol;
    const bf16_t* gB = B + (n0 + srow) * K_DIM + scol;
    bf16_t* lA = As + wid * 2048;   // +i*512 elems (= i*1024 bytes), wave-uniform
    bf16_t* lB = Bs + wid * 2048;

    const f32x4 zero = {0.f, 0.f, 0.f, 0.f};
    f32x4 acc[4][4];
    #pragma unroll
    for (int i = 0; i < 4; ++i)
        #pragma unroll
        for (int j = 0; j < 4; ++j) acc[i][j] = zero;

    for (int kt = 0; kt < K_DIM; kt += BK) {
        #pragma unroll
        for (int i = 0; i < 4; ++i) {
            __builtin_amdgcn_global_load_lds(
                (const __attribute__((address_space(1))) void*)(gA + (long long)i * 8 * K_DIM + kt),
                (__attribute__((address_space(3))) void*)(lA + i * 512), 16, 0, 0);
        }
        #pragma unroll
        for (int i = 0; i < 4; ++i) {
            __builtin_amdgcn_global_load_lds(
                (const __attribute__((address_space(1))) void*)(gB + (long long)i * 8 * K_DIM + kt),
                (__attribute__((address_space(3))) void*)(lB + i * 512), 16, 0, 0);
        }
        __syncthreads();   // drains vmcnt(0) -> staged tiles visible

        #pragma unroll
        for (int kk = 0; kk < 2; ++kk) {
            const int kc = kk * 32 + (lane >> 4) * 8;
            bf16x8 af[4], bfr[4];
            #pragma unroll
            for (int mi = 0; mi < 4; ++mi)
                af[mi] = *(const bf16x8*)(As + (wr * 64 + mi * 16 + (lane & 15)) * BK + kc);
            #pragma unroll
            for (int ni = 0; ni < 4; ++ni)
                bfr[ni] = *(const bf16x8*)(Bs + (wc * 64 + ni * 16 + (lane & 15)) * BK + kc);
            #pragma unroll
            for (int mi = 0; mi < 4; ++mi)
                #pragma unroll
                for (int ni = 0; ni < 4; ++ni)
                    acc[mi][ni] = __builtin_amdgcn_mfma_f32_16x16x32_bf16(
                        af[mi], bfr[ni], acc[mi][ni], 0, 0, 0);
        }
        __syncthreads();   // all reads done before next-tile overwrite
    }

    // epilogue: C/D layout col=lane&15, row=(lane>>4)*4+reg  [m89/m91 verified]
    float sc[4];
    #pragma unroll
    for (int ni = 0; ni < 4; ++ni)
        sc[ni] = scale[n0 + wc * 64 + ni * 16 + (lane & 15)];

    #pragma unroll
    for (int mi = 0; mi < 4; ++mi) {
        const long long rowb = m0 + wr * 64 + mi * 16 + (lane >> 4) * 4;
        #pragma unroll
        for (int ni = 0; ni < 4; ++ni) {
            const long long col = n0 + wc * 64 + ni * 16 + (lane & 15);
            #pragma unroll
            for (int j = 0; j < 4; ++j)
                C[(rowb + j) * N_DIM + col] = acc[mi][ni][j] * sc[ni];
        }
    }
}

// ---------------------------------------------------------------------------
// Fallback (only if ws too small): single-pass naive, slow but correct.
// ---------------------------------------------------------------------------
__global__ void bitlinear_naive_kernel(const float* __restrict__ x,
                                       const float* __restrict__ w,
                                       float* __restrict__ out, long long total) {
    const long long idx = (long long)blockIdx.x * blockDim.x + threadIdx.x;
    if (idx >= total) return;
    const long long m = idx / N_DIM;
    const long long o = idx % N_DIM;
    const float* xr = x + m * K_DIM;
    const float* wrow = w + o * K_DIM;
    float sum = 0.f, sa = 0.f;
    for (int k = 0; k < K_DIM; ++k) {
        float wv = wrow[k];
        sa += fabsf(wv);
        float sg = (wv > 0.f) ? 1.f : ((wv < 0.f) ? -1.f : 0.f);
        sum += xr[k] * sg;
    }
    out[idx] = sum * (sa * (1.0f / (float)K_DIM));
}

// ---------------------------------------------------------------------------
extern "C" void kernel_launch(void* const* d_in, const int* in_sizes, int n_in,
                              void* d_out, int out_size, void* d_ws, size_t ws_size,
                              hipStream_t stream) {
    const float* x = (const float*)d_in[0];   // [B,S,K] fp32
    const float* w = (const float*)d_in[1];   // [N,K] fp32
    float* out = (float*)d_out;               // [B,S,N] fp32

    const int M = in_sizes[0] / K_DIM;        // 8192

    const size_t xb_bytes = (size_t)M * K_DIM * sizeof(bf16_t);
    const size_t wb_bytes = (size_t)N_DIM * K_DIM * sizeof(bf16_t);
    const size_t s_bytes  = (size_t)N_DIM * sizeof(float);

    if (ws_size < xb_bytes + wb_bytes + s_bytes) {
        // emergency correctness fallback (no workspace needed)
        const long long total = (long long)M * N_DIM;
        const int blocks = (int)((total + 255) / 256);
        bitlinear_naive_kernel<<<blocks, 256, 0, stream>>>(x, w, out, total);
        return;
    }

    bf16_t* xb = (bf16_t*)d_ws;
    bf16_t* wb = (bf16_t*)((char*)d_ws + xb_bytes);
    float*  s  = (float*)((char*)d_ws + xb_bytes + wb_bytes);

    // 1) x -> bf16
    {
        const int n8 = (M * K_DIM) / 8;          // 4,194,304
        convert_x_kernel<<<n8 / 256, 256, 0, stream>>>(x, xb);
    }
    // 2) w -> sign bf16 + per-row scale
    convert_w_kernel<<<N_DIM, 256, 0, stream>>>(w, wb, s);
    // 3) GEMM + scale epilogue
    {
        const int grid = (M / 128) * (N_DIM / 128);   // 64 * 32 = 2048
        bitlinear_gemm_kernel<<<grid, 256, 0, stream>>>(xb, wb, s, out, M);
    }
}

// Round 2
// 268.838 us; speedup vs baseline: 1.5470x; 1.5470x over previous
//
#include <hip/hip_runtime.h>
#include <hip/hip_bf16.h>
#include <stdint.h>

typedef __bf16 bf16_t;
typedef __bf16 bf16x8 __attribute__((ext_vector_type(8)));
typedef float  f32x4  __attribute__((ext_vector_type(4)));

#define K_DIM 4096
#define N_DIM 4096

// ---------------------------------------------------------------------------
// Kernel 1: x fp32 -> bf16
// ---------------------------------------------------------------------------
__global__ __launch_bounds__(256) void convert_x_kernel(const float* __restrict__ x,
                                                        bf16_t* __restrict__ xb) {
    const long long i = ((long long)blockIdx.x * blockDim.x + threadIdx.x) * 8;
    float4 a = *(const float4*)(x + i);
    float4 b = *(const float4*)(x + i + 4);
    bf16x8 o;
    o[0] = (bf16_t)a.x; o[1] = (bf16_t)a.y; o[2] = (bf16_t)a.z; o[3] = (bf16_t)a.w;
    o[4] = (bf16_t)b.x; o[5] = (bf16_t)b.y; o[6] = (bf16_t)b.z; o[7] = (bf16_t)b.w;
    *(bf16x8*)(xb + i) = o;
}

// ---------------------------------------------------------------------------
// Kernel 2: weight row -> sign (bf16, exact) + per-row mean|w| (fp32)
// ---------------------------------------------------------------------------
__device__ __forceinline__ bf16_t sgn_bf16(float f) {
    return (bf16_t)((f > 0.f) ? 1.f : ((f < 0.f) ? -1.f : 0.f));
}

__global__ __launch_bounds__(256) void convert_w_kernel(const float* __restrict__ w,
                                                        bf16_t* __restrict__ wb,
                                                        float* __restrict__ s) {
    const int row = blockIdx.x;
    const int tid = threadIdx.x;
    const float* wr = w + (long long)row * K_DIM;
    bf16_t* wbr = wb + (long long)row * K_DIM;
    const int off = tid * 16;

    float sum = 0.f;
    bf16x8 o0, o1;
    #pragma unroll
    for (int j = 0; j < 2; ++j) {
        float4 v = *(const float4*)(wr + off + j * 4);
        sum += fabsf(v.x) + fabsf(v.y) + fabsf(v.z) + fabsf(v.w);
        o0[j * 4 + 0] = sgn_bf16(v.x); o0[j * 4 + 1] = sgn_bf16(v.y);
        o0[j * 4 + 2] = sgn_bf16(v.z); o0[j * 4 + 3] = sgn_bf16(v.w);
    }
    #pragma unroll
    for (int j = 0; j < 2; ++j) {
        float4 v = *(const float4*)(wr + off + 8 + j * 4);
        sum += fabsf(v.x) + fabsf(v.y) + fabsf(v.z) + fabsf(v.w);
        o1[j * 4 + 0] = sgn_bf16(v.x); o1[j * 4 + 1] = sgn_bf16(v.y);
        o1[j * 4 + 2] = sgn_bf16(v.z); o1[j * 4 + 3] = sgn_bf16(v.w);
    }
    *(bf16x8*)(wbr + off)     = o0;
    *(bf16x8*)(wbr + off + 8) = o1;

    #pragma unroll
    for (int d = 32; d > 0; d >>= 1) sum += __shfl_down(sum, d);
    __shared__ float red[4];
    const int lane = tid & 63, wid = tid >> 6;
    if (lane == 0) red[wid] = sum;
    __syncthreads();
    if (tid == 0) s[row] = (red[0] + red[1] + red[2] + red[3]) * (1.0f / (float)K_DIM);
}

// ===========================================================================
// 256x256 8-phase GEMM (T1+T2+T3+T4+T5 stack)
//   C[m][n] = scale[n] * sum_k A[m][k]*B[n][k]
// LDS: 2 dbuf x (A 256x64 + B 256x64) bf16 = 128 KiB (dynamic).
// Swizzle: element (row,col) stored at colbytes ^ ((row&7)<<4); achieved via
// inverse-swizzled per-lane GLOBAL source (gload_lds dest stays linear).
// ===========================================================================
struct SOp { const bf16_t* g; int row0; int kt; bf16_t* l; };

__device__ __forceinline__ void stage_half(const SOp s, int wid, int lane) {
    // one 128-row x 64-col half-tile: 8 waves x 2 gload_lds x 64 lanes x 16B
    const int r  = s.row0 + wid * 16 + (lane >> 3);
    const int ce = s.kt + (((lane & 7) ^ (lane >> 3)) << 3);  // pre-swizzled src col
    const bf16_t* src0 = s.g + (long long)r * K_DIM + ce;
    __builtin_amdgcn_global_load_lds(
        (const __attribute__((address_space(1))) void*)src0,
        (__attribute__((address_space(3))) void*)(s.l + wid * 1024), 16, 0, 0);
    __builtin_amdgcn_global_load_lds(
        (const __attribute__((address_space(1))) void*)(src0 + (long long)8 * K_DIM),
        (__attribute__((address_space(3))) void*)(s.l + wid * 1024 + 512), 16, 0, 0);
}

__device__ __forceinline__ bf16x8 ldsf(const bf16_t* t, int row, int kk, int kb) {
    // read 8 bf16 of element-cols kk*32 + (lane>>4)*8, swizzled
    const int cb = (kk * 64 + kb) ^ ((row & 7) << 4);
    return *(const bf16x8*)((const char*)t + row * 128 + cb);
}

// one K-tile = 4 phases. Reads: P0 a0+b0(12), P1 b1(4), P2 a1(8), P3 none.
// Quadrants: P0 a0xb0, P1 a0xb1, P2 a1xb0, P3 a1xb1 (16 MFMA each).
template<bool S0, bool S1, bool S2, bool S3, int WN>
__device__ __forceinline__ void kgroup(const bf16_t* __restrict__ tA,
                                       const bf16_t* __restrict__ tB,
                                       SOp s0, SOp s1, SOp s2, SOp s3,
                                       f32x4 (&acc)[8][4],
                                       int wm, int wn, int wid, int lane)
{
    const int l15 = lane & 15;
    const int kb  = (lane >> 4) * 16;
    bf16x8 a0[4][2], a1[4][2], b0[2][2], b1[2][2];

    // ---- P0: read a0 (mi 0-3) + b0 (ni 0-1); stage; MFMA q(0,0)
    #pragma unroll
    for (int mi = 0; mi < 4; ++mi) {
        const int row = wm * 128 + mi * 16 + l15;
        #pragma unroll
        for (int kk = 0; kk < 2; ++kk) a0[mi][kk] = ldsf(tA, row, kk, kb);
    }
    #pragma unroll
    for (int ni = 0; ni < 2; ++ni) {
        const int row = wn * 64 + ni * 16 + l15;
        #pragma unroll
        for (int kk = 0; kk < 2; ++kk) b0[ni][kk] = ldsf(tB, row, kk, kb);
    }
    if constexpr (S0) stage_half(s0, wid, lane);
    __builtin_amdgcn_s_barrier();
    __builtin_amdgcn_s_setprio(1);
    #pragma unroll
    for (int kk = 0; kk < 2; ++kk)
        #pragma unroll
        for (int mi = 0; mi < 4; ++mi)
            #pragma unroll
            for (int ni = 0; ni < 2; ++ni)
                acc[mi][ni] = __builtin_amdgcn_mfma_f32_16x16x32_bf16(
                    a0[mi][kk], b0[ni][kk], acc[mi][ni], 0, 0, 0);
    __builtin_amdgcn_s_setprio(0);
    __builtin_amdgcn_s_barrier();

    // ---- P1: read b1 (ni 2-3); stage; MFMA q(0,1)
    #pragma unroll
    for (int ni = 0; ni < 2; ++ni) {
        const int row = wn * 64 + 32 + ni * 16 + l15;
        #pragma unroll
        for (int kk = 0; kk < 2; ++kk) b1[ni][kk] = ldsf(tB, row, kk, kb);
    }
    if constexpr (S1) stage_half(s1, wid, lane);
    __builtin_amdgcn_s_barrier();
    __builtin_amdgcn_s_setprio(1);
    #pragma unroll
    for (int kk = 0; kk < 2; ++kk)
        #pragma unroll
        for (int mi = 0; mi < 4; ++mi)
            #pragma unroll
            for (int ni = 0; ni < 2; ++ni)
                acc[mi][2 + ni] = __builtin_amdgcn_mfma_f32_16x16x32_bf16(
                    a0[mi][kk], b1[ni][kk], acc[mi][2 + ni], 0, 0, 0);
    __builtin_amdgcn_s_setprio(0);
    __builtin_amdgcn_s_barrier();

    // ---- P2: read a1 (mi 4-7); stage; MFMA q(1,0)
    #pragma unroll
    for (int mi = 0; mi < 4; ++mi) {
        const int row = wm * 128 + 64 + mi * 16 + l15;
        #pragma unroll
        for (int kk = 0; kk < 2; ++kk) a1[mi][kk] = ldsf(tA, row, kk, kb);
    }
    if constexpr (S2) stage_half(s2, wid, lane);
    __builtin_amdgcn_s_barrier();
    __builtin_amdgcn_s_setprio(1);
    #pragma unroll
    for (int kk = 0; kk < 2; ++kk)
        #pragma unroll
        for (int mi = 0; mi < 4; ++mi)
            #pragma unroll
            for (int ni = 0; ni < 2; ++ni)
                acc[4 + mi][ni] = __builtin_amdgcn_mfma_f32_16x16x32_bf16(
                    a1[mi][kk], b0[ni][kk], acc[4 + mi][ni], 0, 0, 0);
    __builtin_amdgcn_s_setprio(0);
    __builtin_amdgcn_s_barrier();

    // ---- P3: stage; MFMA q(1,1); counted vmcnt; barrier
    if constexpr (S3) stage_half(s3, wid, lane);
    __builtin_amdgcn_s_barrier();
    __builtin_amdgcn_s_setprio(1);
    #pragma unroll
    for (int kk = 0; kk < 2; ++kk)
        #pragma unroll
        for (int mi = 0; mi < 4; ++mi)
            #pragma unroll
            for (int ni = 0; ni < 2; ++ni)
                acc[4 + mi][2 + ni] = __builtin_amdgcn_mfma_f32_16x16x32_bf16(
                    a1[mi][kk], b1[ni][kk], acc[4 + mi][2 + ni], 0, 0, 0);
    __builtin_amdgcn_s_setprio(0);
    if constexpr (WN == 0)      asm volatile("s_waitcnt vmcnt(0)" ::: "memory");
    else if constexpr (WN == 2) asm volatile("s_waitcnt vmcnt(2)" ::: "memory");
    if constexpr (WN >= 0) __builtin_amdgcn_s_barrier();
}

__global__ __launch_bounds__(512, 2) void bitlinear_gemm256(
    const bf16_t* __restrict__ A, const bf16_t* __restrict__ B,
    const float* __restrict__ scale, float* __restrict__ C, int M)
{
    extern __shared__ bf16_t smem[];
    bf16_t* As0 = smem;                 // [256][64]
    bf16_t* As1 = smem + 16384;
    bf16_t* Bs0 = smem + 32768;
    bf16_t* Bs1 = smem + 49152;

    const int tid = threadIdx.x, lane = tid & 63, wid = tid >> 6;
    const int wm = wid >> 2, wn = wid & 3;

    // T1: bijective XCD swizzle (grid % 8 == 0 guaranteed by launcher)
    const int nbid = (int)blockIdx.x;
    const int cpx  = (int)gridDim.x >> 3;
    const int swz  = (nbid & 7) * cpx + (nbid >> 3);
    const int ntn  = N_DIM / 256;       // 16
    const int tm = swz / ntn, tn = swz % ntn;

    const bf16_t* gA = A + (long long)tm * 256 * K_DIM;
    const bf16_t* gB = B + (long long)tn * 256 * K_DIM;

    const f32x4 zero = {0.f, 0.f, 0.f, 0.f};
    f32x4 acc[8][4];
    #pragma unroll
    for (int i = 0; i < 8; ++i)
        #pragma unroll
        for (int j = 0; j < 4; ++j) acc[i][j] = zero;

    // prologue: tile0 (all 4 halves) + tile1 h0; wait oldest 8; barrier
    stage_half({gA,   0,  0, As0},        wid, lane);
    stage_half({gA, 128,  0, As0 + 8192}, wid, lane);
    stage_half({gB,   0,  0, Bs0},        wid, lane);
    stage_half({gB, 128,  0, Bs0 + 8192}, wid, lane);
    stage_half({gA,   0, 64, As1},        wid, lane);
    asm volatile("s_waitcnt vmcnt(2)" ::: "memory");
    __builtin_amdgcn_s_barrier();

    // main loop: 31 iters x 2 K-tiles; stages run 1.5 tiles ahead
    #pragma unroll 1
    for (int i = 0; i < 31; ++i) {
        const int kt = i * 128;
        // compute tile 2i (buf0); stage tile 2i+1 h1,h2,h3 + tile 2i+2 h0
        kgroup<true, true, true, true, 2>(As0, Bs0,
            {gA, 128, kt + 64,  As1 + 8192},
            {gB,   0, kt + 64,  Bs1},
            {gB, 128, kt + 64,  Bs1 + 8192},
            {gA,   0, kt + 128, As0},
            acc, wm, wn, wid, lane);
        // compute tile 2i+1 (buf1); stage tile 2i+2 h1,h2,h3 + tile 2i+3 h0
        kgroup<true, true, true, true, 2>(As1, Bs1,
            {gA, 128, kt + 128, As0 + 8192},
            {gB,   0, kt + 128, Bs0},
            {gB, 128, kt + 128, Bs0 + 8192},
            {gA,   0, kt + 192, As1},
            acc, wm, wn, wid, lane);
    }
    // peeled tail: tiles 62, 63
    {
        const int kt = 31 * 128;
        kgroup<true, true, true, false, 0>(As0, Bs0,
            {gA, 128, kt + 64, As1 + 8192},
            {gB,   0, kt + 64, Bs1},
            {gB, 128, kt + 64, Bs1 + 8192},
            {gA,   0, 0,       As0},
            acc, wm, wn, wid, lane);
        kgroup<false, false, false, false, -1>(As1, Bs1,
            {gA, 0, 0, As0}, {gA, 0, 0, As0}, {gA, 0, 0, As0}, {gA, 0, 0, As0},
            acc, wm, wn, wid, lane);
    }

    // epilogue: scale + store. C/D layout: col=lane&15, row=(lane>>4)*4+j
    const long long m0 = (long long)tm * 256 + wm * 128;
    const long long n0 = (long long)tn * 256 + wn * 64;
    float sc[4];
    #pragma unroll
    for (int ni = 0; ni < 4; ++ni) sc[ni] = scale[n0 + ni * 16 + (lane & 15)];
    #pragma unroll
    for (int mi = 0; mi < 8; ++mi) {
        const long long rowb = m0 + mi * 16 + (lane >> 4) * 4;
        #pragma unroll
        for (int ni = 0; ni < 4; ++ni) {
            const long long col = n0 + ni * 16 + (lane & 15);
            #pragma unroll
            for (int j = 0; j < 4; ++j)
                C[(rowb + j) * N_DIM + col] = acc[mi][ni][j] * sc[ni];
        }
    }
}

// ---------------------------------------------------------------------------
// Proven round-1 128x128 GEMM — fallback path
// ---------------------------------------------------------------------------
__global__ __launch_bounds__(256) void bitlinear_gemm_kernel(
    const bf16_t* __restrict__ A, const bf16_t* __restrict__ B,
    const float* __restrict__ scale, float* __restrict__ C, int M)
{
    constexpr int BK = 64;
    __shared__ bf16_t As[128 * BK];
    __shared__ bf16_t Bs[128 * BK];

    const int tid  = threadIdx.x;
    const int lane = tid & 63;
    const int wid  = tid >> 6;
    const int wr   = wid >> 1;
    const int wc   = wid & 1;

    const int ntn = N_DIM / 128;
    const int tm  = blockIdx.x / ntn;
    const int tn  = blockIdx.x % ntn;
    const long long m0 = (long long)tm * 128;
    const long long n0 = (long long)tn * 128;

    const int srow = wid * 32 + (lane >> 3);
    const int scol = (lane & 7) * 8;
    const bf16_t* gA = A + (m0 + srow) * K_DIM + scol;
    const bf16_t* gB = B + (n0 + srow) * K_DIM + scol;
    bf16_t* lA = As + wid * 2048;
    bf16_t* lB = Bs + wid * 2048;

    const f32x4 zero = {0.f, 0.f, 0.f, 0.f};
    f32x4 acc[4][4];
    #pragma unroll
    for (int i = 0; i < 4; ++i)
        #pragma unroll
        for (int j = 0; j < 4; ++j) acc[i][j] = zero;

    for (int kt = 0; kt < K_DIM; kt += BK) {
        #pragma unroll
        for (int i = 0; i < 4; ++i)
            __builtin_amdgcn_global_load_lds(
                (const __attribute__((address_space(1))) void*)(gA + (long long)i * 8 * K_DIM + kt),
                (__attribute__((address_space(3))) void*)(lA + i * 512), 16, 0, 0);
        #pragma unroll
        for (int i = 0; i < 4; ++i)
            __builtin_amdgcn_global_load_lds(
                (const __attribute__((address_space(1))) void*)(gB + (long long)i * 8 * K_DIM + kt),
                (__attribute__((address_space(3))) void*)(lB + i * 512), 16, 0, 0);
        __syncthreads();

        #pragma unroll
        for (int kk = 0; kk < 2; ++kk) {
            const int kc = kk * 32 + (lane >> 4) * 8;
            bf16x8 af[4], bfr[4];
            #pragma unroll
            for (int mi = 0; mi < 4; ++mi)
                af[mi] = *(const bf16x8*)(As + (wr * 64 + mi * 16 + (lane & 15)) * BK + kc);
            #pragma unroll
            for (int ni = 0; ni < 4; ++ni)
                bfr[ni] = *(const bf16x8*)(Bs + (wc * 64 + ni * 16 + (lane & 15)) * BK + kc);
            #pragma unroll
            for (int mi = 0; mi < 4; ++mi)
                #pragma unroll
                for (int ni = 0; ni < 4; ++ni)
                    acc[mi][ni] = __builtin_amdgcn_mfma_f32_16x16x32_bf16(
                        af[mi], bfr[ni], acc[mi][ni], 0, 0, 0);
        }
        __syncthreads();
    }

    float sc[4];
    #pragma unroll
    for (int ni = 0; ni < 4; ++ni)
        sc[ni] = scale[n0 + wc * 64 + ni * 16 + (lane & 15)];
    #pragma unroll
    for (int mi = 0; mi < 4; ++mi) {
        const long long rowb = m0 + wr * 64 + mi * 16 + (lane >> 4) * 4;
        #pragma unroll
        for (int ni = 0; ni < 4; ++ni) {
            const long long col = n0 + wc * 64 + ni * 16 + (lane & 15);
            #pragma unroll
            for (int j = 0; j < 4; ++j)
                C[(rowb + j) * N_DIM + col] = acc[mi][ni][j] * sc[ni];
        }
    }
}

__global__ void bitlinear_naive_kernel(const float* __restrict__ x,
                                       const float* __restrict__ w,
                                       float* __restrict__ out, long long total) {
    const long long idx = (long long)blockIdx.x * blockDim.x + threadIdx.x;
    if (idx >= total) return;
    const long long m = idx / N_DIM;
    const long long o = idx % N_DIM;
    const float* xr = x + m * K_DIM;
    const float* wrow = w + o * K_DIM;
    float sum = 0.f, sa = 0.f;
    for (int k = 0; k < K_DIM; ++k) {
        float wv = wrow[k];
        sa += fabsf(wv);
        sum += xr[k] * ((wv > 0.f) ? 1.f : ((wv < 0.f) ? -1.f : 0.f));
    }
    out[idx] = sum * (sa * (1.0f / (float)K_DIM));
}

// ---------------------------------------------------------------------------
extern "C" void kernel_launch(void* const* d_in, const int* in_sizes, int n_in,
                              void* d_out, int out_size, void* d_ws, size_t ws_size,
                              hipStream_t stream) {
    const float* x = (const float*)d_in[0];
    const float* w = (const float*)d_in[1];
    float* out = (float*)d_out;

    const int M = in_sizes[0] / K_DIM;

    const size_t xb_bytes = (size_t)M * K_DIM * sizeof(bf16_t);
    const size_t wb_bytes = (size_t)N_DIM * K_DIM * sizeof(bf16_t);
    const size_t s_bytes  = (size_t)N_DIM * sizeof(float);

    if (ws_size < xb_bytes + wb_bytes + s_bytes || (M % 128) != 0) {
        const long long total = (long long)M * N_DIM;
        bitlinear_naive_kernel<<<(int)((total + 255) / 256), 256, 0, stream>>>(x, w, out, total);
        return;
    }

    bf16_t* xb = (bf16_t*)d_ws;
    bf16_t* wb = (bf16_t*)((char*)d_ws + xb_bytes);
    float*  s  = (float*)((char*)d_ws + xb_bytes + wb_bytes);

    convert_x_kernel<<<(M * (K_DIM / 8)) / 256, 256, 0, stream>>>(x, xb);
    convert_w_kernel<<<N_DIM, 256, 0, stream>>>(w, wb, s);

    bool use256 = (M % 256) == 0;
    if (use256) {
        hipError_t e = hipFuncSetAttribute((const void*)bitlinear_gemm256,
                                           hipFuncAttributeMaxDynamicSharedMemorySize,
                                           131072);
        if (e != hipSuccess) use256 = false;
    }
    if (use256) {
        const int grid = (M / 256) * (N_DIM / 256);   // 32*16 = 512, %8==0
        bitlinear_gemm256<<<grid, 512, 131072, stream>>>(xb, wb, s, out, M);
    } else {
        const int grid = (M / 128) * (N_DIM / 128);
        bitlinear_gemm_kernel<<<grid, 256, 0, stream>>>(xb, wb, s, out, M);
    }
}